// Round 6
// baseline (4306.844 us; speedup 1.0000x reference)
//
#include <hip/hip_runtime.h>

#define B_SZ 512
#define S_SZ 256
#define D_SZ 512
#define H_SZ 512

typedef __bf16 bf16x8 __attribute__((ext_vector_type(8)));
typedef __bf16 bf16x4 __attribute__((ext_vector_type(4)));
typedef float f32x4 __attribute__((ext_vector_type(4)));
typedef unsigned u32x4 __attribute__((ext_vector_type(4)));
typedef unsigned long long u64;

// ---------------- ws layout (bytes) ----------------
// [0, 32KB)       : step flags: 8 groups x 32 WG-slots x 128B
// [32KB, 64KB)    : xcc flags:  8 groups x 32 WG-slots x 128B
// [64KB, +1MB)    : state parity 0: h0 (512x512 bf16) then cf0 (c*f_att)
// [+1MB, +2MB)    : state parity 1
// [2162688, +4MB) : GwT 4*512*1024 bf16 (g, j, k)
// [6356992, +.5MB): WeT 512*512 bf16 (j, k)
#define FLAGS_BYTES 65536
#define STATE_OFF FLAGS_BYTES
#define STATE_PAR_ELEMS (2 * H_SZ * B_SZ)
#define GWT_OFF_BYTES (STATE_OFF + 2097152)
#define WET_OFF_BYTES (GWT_OFF_BYTES + 4194304)

// XOR swizzle: 2-way max bank aliasing on ds_read_b128 (free per m136)
#define SWZ(j, k) ((k) ^ (((j) & 7) << 3) ^ ((((j) >> 3) & 1) << 6))

template <bool V> struct BoolC { static constexpr bool value = V; };

__device__ __forceinline__ float sigmoidf_(float v) {
    return 1.f / (1.f + __expf(-v));
}
__device__ __forceinline__ float tanhf_(float v) {
    return 1.f - 2.f / (1.f + __expf(2.f * v));
}

// LLC-coherent accesses (fallback path): relaxed agent atomics -> sc0 sc1,
// no cache flushes, compiler-correct vmcnt tracking.
__device__ __forceinline__ u64 coh_load(const u64* p) {
    return __hip_atomic_load(p, __ATOMIC_RELAXED, __HIP_MEMORY_SCOPE_AGENT);
}
__device__ __forceinline__ void coh_store(u64* p, u64 v) {
    __hip_atomic_store(p, v, __ATOMIC_RELAXED, __HIP_MEMORY_SCOPE_AGENT);
}

__global__ __launch_bounds__(256) void prep_weights(
    const float* __restrict__ We,
    const float* __restrict__ Ui, const float* __restrict__ Vi,
    const float* __restrict__ Uf, const float* __restrict__ Vf,
    const float* __restrict__ Uc, const float* __restrict__ Vc,
    const float* __restrict__ Uo, const float* __restrict__ Vo,
    __bf16* __restrict__ GwT, __bf16* __restrict__ WeT)
{
    const int bid = blockIdx.x;
    const int tid = threadIdx.x;
    if (bid < 2048) {
        const int g = bid >> 9;
        const int j = bid & 511;
        const float* U = (g == 0) ? Ui : (g == 1) ? Uf : (g == 2) ? Uc : Uo;
        const float* V = (g == 0) ? Vi : (g == 1) ? Vf : (g == 2) ? Vc : Vo;
        __bf16* dst = GwT + ((size_t)(g * 512 + j) << 10);
        for (int k = tid; k < 1024; k += 256) {
            float v = (k < 512) ? U[k * 512 + j] : V[(k - 512) * 512 + j];
            dst[k] = (__bf16)v;
        }
    } else {
        const int j = bid - 2048;
        __bf16* dst = WeT + ((size_t)j << 9);
        for (int k = tid; k < 512; k += 256) {
            dst[k] = (__bf16)We[k * 512 + j];
        }
    }
}

// Persistent recurrent kernel. 256 WGs x 256 thr, 1 WG/CU (144KB LDS).
// WG (rblk=bid&7, cblk=bid>>3): batch rows [rblk*64,+64) x cols [cblk*16,+16).
// State exchange: if the whole group shares one XCD (verified at runtime via
// HW_REG_XCC_ID), use volatile 16B loads / 8B stores (L1-bypass, L2-coherent
// intra-XCD, half the instructions). Else: AGENT-atomic LLC path (always
// correct regardless of dispatch mapping).
__global__ __launch_bounds__(256, 1) void lstm_persist(
    const float* __restrict__ x, const float* __restrict__ tseq,
    const float* __restrict__ b_i, const float* __restrict__ b_f,
    const float* __restrict__ b_c, const float* __restrict__ b_o,
    const float* __restrict__ b_e,
    const __bf16* __restrict__ GwT, const __bf16* __restrict__ WeT,
    __bf16* __restrict__ state, int* __restrict__ flags,
    float* __restrict__ out)
{
    __shared__ __align__(16) __bf16 wlds[4][16][1024];
    __shared__ __align__(16) __bf16 welds[16][512];

    const int tid = threadIdx.x;
    const int bid = blockIdx.x;
    const int rblk = bid & 7;
    const int cblk = bid >> 3;
    const int j0 = cblk << 4;
    const int wave = tid >> 6;
    const int lane = tid & 63;
    const int alr = lane & 15;   // weight row j (A-frag row)
    const int hq = lane >> 4;    // k-subgroup / C j-quad
    const int kbase = hq * 8;

    // ---- stage weights into LDS, swizzled (once) ----
    for (int e = tid * 8; e < 4 * 16 * 1024; e += 256 * 8) {
        const int g = e >> 14;
        const int j = (e >> 10) & 15;
        const int k = e & 1023;
        *(uint4*)&wlds[g][j][SWZ(j, k)] =
            *(const uint4*)&GwT[((size_t)(g * 512 + j0 + j) << 10) + k];
    }
    for (int e = tid * 8; e < 16 * 512; e += 256 * 8) {
        const int j = e >> 9;
        const int k = e & 511;
        *(uint4*)&welds[j][SWZ(j, k)] =
            *(const uint4*)&WeT[((size_t)(j0 + j) << 9) + k];
    }
    __syncthreads();

    // gates k<256 weight fragments in registers (128 VGPR)
    bf16x8 wxr[8][4];
    #pragma unroll
    for (int kk = 0; kk < 8; ++kk)
        #pragma unroll
        for (int g = 0; g < 4; ++g)
            wxr[kk][g] = *(const bf16x8*)&wlds[g][alr][SWZ(alr, kk * 32 + kbase)];

    const int brow = rblk * 64 + wave * 16 + alr;   // batch row
    const int jbase = j0 + hq * 4;                   // 4 consecutive j (C rows)
    const f32x4 Bi4 = *(const f32x4*)(b_i + jbase);
    const f32x4 Bf4 = *(const f32x4*)(b_f + jbase);
    const f32x4 Bc4 = *(const f32x4*)(b_c + jbase);
    const f32x4 Bo4 = *(const f32x4*)(b_o + jbase);
    const f32x4 Be4 = *(const f32x4*)(b_e + jbase);

    const float* xrow = x + (size_t)brow * S_SZ * D_SZ;
    const float* tsrow = tseq + (size_t)brow * S_SZ;
    const size_t hoff = (size_t)brow * H_SZ;
    float* outrow = out + (size_t)brow * S_SZ * H_SZ + jbase;

    // step-flag slots (128B stride) + poll address for this lane
    int* gflags = flags + (size_t)rblk * 32 * 32;
    int* myflag = gflags + (size_t)cblk * 32;
    const int* pollp = gflags + (size_t)(lane & 31) * 32;

    // ---- XCD-locality check: does my whole group share one XCD? ----
    int* xgrp = flags + 8192 + (size_t)rblk * 32 * 32;
    unsigned xcc;
    asm volatile("s_getreg_b32 %0, hwreg(HW_REG_XCC_ID)" : "=s"(xcc));
    if (tid == 0)
        __hip_atomic_store(xgrp + (size_t)cblk * 32, (int)xcc + 1,
                           __ATOMIC_RELAXED, __HIP_MEMORY_SCOPE_AGENT);
    int vx;
    const int* xpoll = xgrp + (size_t)(lane & 31) * 32;
    for (;;) {
        vx = __hip_atomic_load(xpoll, __ATOMIC_RELAXED, __HIP_MEMORY_SCOPE_AGENT);
        if (__all(vx != 0)) break;
        __builtin_amdgcn_s_sleep(1);
    }
    const bool l2ok = __all(vx == __shfl(vx, 0, 64));

    // prologue: load + convert x[0]
    bf16x8 xbf[16];
    {
        f32x4 xf[32];
        #pragma unroll
        for (int kk = 0; kk < 16; ++kk) {
            xf[2 * kk]     = *(const f32x4*)(xrow + kk * 32 + kbase);
            xf[2 * kk + 1] = *(const f32x4*)(xrow + kk * 32 + kbase + 4);
        }
        #pragma unroll
        for (int kk = 0; kk < 16; ++kk) {
            f32x4 u = xf[2 * kk], v = xf[2 * kk + 1];
            bf16x8 a;
            a[0] = (__bf16)u[0]; a[1] = (__bf16)u[1]; a[2] = (__bf16)u[2]; a[3] = (__bf16)u[3];
            a[4] = (__bf16)v[0]; a[5] = (__bf16)v[1]; a[6] = (__bf16)v[2]; a[7] = (__bf16)v[3];
            xbf[kk] = a;
        }
    }

    auto run = [&](auto l2c) {
        constexpr bool L2 = decltype(l2c)::value;
        for (int t = 0; t < S_SZ; ++t) {
            const __bf16* hp = state + (size_t)(t & 1) * STATE_PAR_ELEMS;
            const __bf16* cp = hp + (size_t)H_SZ * B_SZ;
            __bf16* hnx = state + (size_t)((t + 1) & 1) * STATE_PAR_ELEMS;
            __bf16* cnx = hnx + (size_t)H_SZ * B_SZ;

            // 1. issue all state loads up front
            union HU { u32x4 q; u64 u[2]; bf16x8 v; };
            HU hs[16], cs[16];
            #pragma unroll
            for (int kk = 0; kk < 16; ++kk) {
                const __bf16* ph = hp + hoff + kbase + kk * 32;
                const __bf16* pc = cp + hoff + kbase + kk * 32;
                if constexpr (L2) {
                    hs[kk].q = *(const volatile u32x4*)ph;
                    cs[kk].q = *(const volatile u32x4*)pc;
                } else {
                    hs[kk].u[0] = coh_load((const u64*)ph);
                    hs[kk].u[1] = coh_load((const u64*)ph + 1);
                    cs[kk].u[0] = coh_load((const u64*)pc);
                    cs[kk].u[1] = coh_load((const u64*)pc + 1);
                }
            }

            // accumulators pre-seeded with biases
            f32x4 a0 = Bi4, a1 = Bf4, a2 = Bc4, a3 = Bo4, a4 = Be4;

            // 2. x@U MFMAs while state loads fly (kk<8 weights from regs)
            #pragma unroll
            for (int kk = 0; kk < 16; ++kk) {
                bf16x8 w0, w1, w2, w3;
                if (kk < 8) {
                    w0 = wxr[kk][0]; w1 = wxr[kk][1]; w2 = wxr[kk][2]; w3 = wxr[kk][3];
                } else {
                    const int k = SWZ(alr, kk * 32 + kbase);
                    w0 = *(const bf16x8*)&wlds[0][alr][k];
                    w1 = *(const bf16x8*)&wlds[1][alr][k];
                    w2 = *(const bf16x8*)&wlds[2][alr][k];
                    w3 = *(const bf16x8*)&wlds[3][alr][k];
                }
                a0 = __builtin_amdgcn_mfma_f32_16x16x32_bf16(w0, xbf[kk], a0, 0, 0, 0);
                a1 = __builtin_amdgcn_mfma_f32_16x16x32_bf16(w1, xbf[kk], a1, 0, 0, 0);
                a2 = __builtin_amdgcn_mfma_f32_16x16x32_bf16(w2, xbf[kk], a2, 0, 0, 0);
                a3 = __builtin_amdgcn_mfma_f32_16x16x32_bf16(w3, xbf[kk], a3, 0, 0, 0);
            }

            // 3. h@V + cf@W_e (compiler inserts per-use vmcnt waits)
            #pragma unroll
            for (int kk = 0; kk < 16; ++kk) {
                const int k = SWZ(alr, 512 + kk * 32 + kbase);
                bf16x8 w0 = *(const bf16x8*)&wlds[0][alr][k];
                bf16x8 w1 = *(const bf16x8*)&wlds[1][alr][k];
                bf16x8 w2 = *(const bf16x8*)&wlds[2][alr][k];
                bf16x8 w3 = *(const bf16x8*)&wlds[3][alr][k];
                bf16x8 we = *(const bf16x8*)&welds[alr][SWZ(alr, kk * 32 + kbase)];
                a0 = __builtin_amdgcn_mfma_f32_16x16x32_bf16(w0, hs[kk].v, a0, 0, 0, 0);
                a1 = __builtin_amdgcn_mfma_f32_16x16x32_bf16(w1, hs[kk].v, a1, 0, 0, 0);
                a2 = __builtin_amdgcn_mfma_f32_16x16x32_bf16(w2, hs[kk].v, a2, 0, 0, 0);
                a3 = __builtin_amdgcn_mfma_f32_16x16x32_bf16(w3, hs[kk].v, a3, 0, 0, 0);
                a4 = __builtin_amdgcn_mfma_f32_16x16x32_bf16(we, cs[kk].v, a4, 0, 0, 0);
            }

            // 4. issue x[t+1] loads (latency hides under elementwise+stores)
            const int tp = (t + 1 < S_SZ) ? t + 1 : t;
            const float* xpn = xrow + (size_t)tp * D_SZ;
            f32x4 xf[32];
            #pragma unroll
            for (int kk = 0; kk < 16; ++kk) {
                xf[2 * kk]     = *(const f32x4*)(xpn + kk * 32 + kbase);
                xf[2 * kk + 1] = *(const f32x4*)(xpn + kk * 32 + kbase + 4);
            }

            // 5. elementwise: lane holds j = jbase..jbase+3, batch row brow
            const float fa = (t + 1 < S_SZ) ? tsrow[t + 1] : 0.f;
            f32x4 hv4, cv4;
            union { bf16x4 v; u64 u; } ph8, pc8;
            #pragma unroll
            for (int e = 0; e < 4; ++e) {
                float it = sigmoidf_(a0[e]);
                float ft = sigmoidf_(a1[e]);
                float gt = tanhf_(a2[e]);
                float ot = sigmoidf_(a3[e]);
                float ctl = tanhf_(a4[e]);
                float cv = ft * ctl + it * gt;
                float hv = ot * tanhf_(cv);
                hv4[e] = hv; cv4[e] = cv;
                ph8.v[e] = (__bf16)hv;
                pc8.v[e] = (__bf16)(cv * fa);
            }
            __builtin_nontemporal_store(hv4, (f32x4*)(outrow + (size_t)t * H_SZ));
            if (t == S_SZ - 1) {
                float* tail = out + (size_t)B_SZ * S_SZ * H_SZ;
                *(f32x4*)(tail + hoff + jbase) = hv4;
                *(f32x4*)(tail + (size_t)B_SZ * H_SZ + hoff + jbase) = cv4;
            }

            // 6. convert x[t+1]
            #pragma unroll
            for (int kk = 0; kk < 16; ++kk) {
                f32x4 u = xf[2 * kk], v = xf[2 * kk + 1];
                bf16x8 a;
                a[0] = (__bf16)u[0]; a[1] = (__bf16)u[1]; a[2] = (__bf16)u[2]; a[3] = (__bf16)u[3];
                a[4] = (__bf16)v[0]; a[5] = (__bf16)v[1]; a[6] = (__bf16)v[2]; a[7] = (__bf16)v[3];
                xbf[kk] = a;
            }

            // 7. publish state
            if constexpr (L2) {
                *(volatile u64*)(hnx + hoff + jbase) = ph8.u;
                *(volatile u64*)(cnx + hoff + jbase) = pc8.u;
            } else {
                coh_store((u64*)(hnx + hoff + jbase), ph8.u);
                coh_store((u64*)(cnx + hoff + jbase), pc8.u);
            }

            // 8. flag barrier: own-slot store, all-waves 64-lane poll
            if (t < S_SZ - 1) {
                __syncthreads();   // vmcnt(0) before s_barrier: stores drained
                if (tid == 0)
                    __hip_atomic_store(myflag, t + 1, __ATOMIC_RELAXED,
                                       __HIP_MEMORY_SCOPE_AGENT);
                const int target = t + 1;
                for (;;) {
                    int v = __hip_atomic_load(pollp, __ATOMIC_RELAXED,
                                              __HIP_MEMORY_SCOPE_AGENT);
                    if (__all(v >= target)) break;
                    __builtin_amdgcn_s_sleep(2);
                }
                __builtin_amdgcn_sched_barrier(0);
            }
        }
    };

    if (l2ok) run(BoolC<true>{});
    else      run(BoolC<false>{});
}

extern "C" void kernel_launch(void* const* d_in, const int* in_sizes, int n_in,
                              void* d_out, int out_size, void* d_ws, size_t ws_size,
                              hipStream_t stream) {
    const float* x  = (const float*)d_in[0];
    const float* ts = (const float*)d_in[1];
    const float* We = (const float*)d_in[2];
    const float* be = (const float*)d_in[3];
    const float* Ui = (const float*)d_in[4];
    const float* Vi = (const float*)d_in[5];
    const float* bi = (const float*)d_in[6];
    const float* Uf = (const float*)d_in[7];
    const float* Vf = (const float*)d_in[8];
    const float* bf = (const float*)d_in[9];
    const float* Uc = (const float*)d_in[10];
    const float* Vc = (const float*)d_in[11];
    const float* bc = (const float*)d_in[12];
    const float* Uo = (const float*)d_in[13];
    const float* Vo = (const float*)d_in[14];
    const float* bo = (const float*)d_in[15];

    char* ws = (char*)d_ws;
    int* flags = (int*)ws;
    __bf16* state = (__bf16*)(ws + STATE_OFF);
    __bf16* GwT = (__bf16*)(ws + GWT_OFF_BYTES);
    __bf16* WeT = (__bf16*)(ws + WET_OFF_BYTES);

    // zero flags (step + xcc) + parity-0 state (h0 = c0 = 0)
    hipMemsetAsync(ws, 0, FLAGS_BYTES + 1048576, stream);
    prep_weights<<<2560, 256, 0, stream>>>(We, Ui, Vi, Uf, Vf, Uc, Vc, Uo, Vo, GwT, WeT);
    lstm_persist<<<256, 256, 0, stream>>>(x, ts, bi, bf, bc, bo, be, GwT, WeT,
                                          state, flags, (float*)d_out);
}

// Round 11
// 2186.996 us; speedup vs baseline: 1.9693x; 1.9693x over previous
//
#include <hip/hip_runtime.h>

#define B_SZ 512
#define S_SZ 256
#define D_SZ 512
#define H_SZ 512

typedef __bf16 bf16x8 __attribute__((ext_vector_type(8)));
typedef __bf16 bf16x4 __attribute__((ext_vector_type(4)));
typedef float f32x4 __attribute__((ext_vector_type(4)));
typedef int i32x4 __attribute__((ext_vector_type(4)));
typedef unsigned long long u64;

// ---------------- ws layout (bytes) ----------------
// [0, 32KB)       : step flags: 8 groups x 32 WG-slots x 128B
// [32KB, 64KB)    : xcc flags:  8 groups x 32 WG-slots x 128B
// [64KB, +1MB)    : state parity 0: h0 (512x512 bf16) then cf0 (c*f_att)
// [+1MB, +2MB)    : state parity 1
// [2162688, +4MB) : GwT 4*512*1024 bf16 (g, j, k)
// [6356992, +.5MB): WeT 512*512 bf16 (j, k)
#define FLAGS_BYTES 65536
#define STATE_OFF FLAGS_BYTES
#define STATE_PAR_ELEMS (2 * H_SZ * B_SZ)
#define GWT_OFF_BYTES (STATE_OFF + 2097152)
#define WET_OFF_BYTES (GWT_OFF_BYTES + 4194304)

// XOR swizzle: 2-way max bank aliasing on ds_read_b128 (free per m136)
#define SWZ(j, k) ((k) ^ (((j) & 7) << 3) ^ ((((j) >> 3) & 1) << 6))

__device__ __forceinline__ float sigmoidf_(float v) {
    return 1.f / (1.f + __expf(-v));
}
__device__ __forceinline__ float tanhf_(float v) {
    return 1.f - 2.f / (1.f + __expf(2.f * v));
}

// LLC-coherent accesses (fallback + flags): relaxed agent atomics -> sc0 sc1,
// no cache flushes, fully compiler-visible. Proven live rounds 2/4/5/6/9/10.
__device__ __forceinline__ u64 coh_load(const u64* p) {
    return __hip_atomic_load(p, __ATOMIC_RELAXED, __HIP_MEMORY_SCOPE_AGENT);
}
__device__ __forceinline__ void coh_store(u64* p, u64 v) {
    __hip_atomic_store(p, v, __ATOMIC_RELAXED, __HIP_MEMORY_SCOPE_AGENT);
}

__global__ __launch_bounds__(256) void prep_weights(
    const float* __restrict__ We,
    const float* __restrict__ Ui, const float* __restrict__ Vi,
    const float* __restrict__ Uf, const float* __restrict__ Vf,
    const float* __restrict__ Uc, const float* __restrict__ Vc,
    const float* __restrict__ Uo, const float* __restrict__ Vo,
    __bf16* __restrict__ GwT, __bf16* __restrict__ WeT)
{
    const int bid = blockIdx.x;
    const int tid = threadIdx.x;
    if (bid < 2048) {
        const int g = bid >> 9;
        const int j = bid & 511;
        const float* U = (g == 0) ? Ui : (g == 1) ? Uf : (g == 2) ? Uc : Uo;
        const float* V = (g == 0) ? Vi : (g == 1) ? Vf : (g == 2) ? Vc : Vo;
        __bf16* dst = GwT + ((size_t)(g * 512 + j) << 10);
        for (int k = tid; k < 1024; k += 256) {
            float v = (k < 512) ? U[k * 512 + j] : V[(k - 512) * 512 + j];
            dst[k] = (__bf16)v;
        }
    } else {
        const int j = bid - 2048;
        __bf16* dst = WeT + ((size_t)j << 9);
        for (int k = tid; k < 512; k += 256) {
            dst[k] = (__bf16)We[k * 512 + j];
        }
    }
}

// Persistent recurrent kernel. 256 WGs x 256 thr, 1 WG/CU (144KB LDS).
// WG (rblk=bid&7, cblk=bid>>3): batch rows [rblk*64,+64) x cols [cblk*16,+16).
// Membership is LOGICAL (bid-based: liveness independent of placement).
// If all 32 group members share one XCD (verified): state exchange via the
// NORMAL cached path (plain write-through stores; plain 16B loads) with an
// explicit per-step vL1 invalidate (`buffer_inv sc0`) after the flag barrier
// -- vL1 is the only incoherent cache inside an XCD, and the rounds-9/10
// identical-staleness result localized the bug to consumer-L1 hits.
// Else: proven agent-atomic LLC path. Flags agent-atomic in both modes.
__global__ __launch_bounds__(256, 1) void lstm_persist(
    const float* __restrict__ x, const float* __restrict__ tseq,
    const float* __restrict__ b_i, const float* __restrict__ b_f,
    const float* __restrict__ b_c, const float* __restrict__ b_o,
    const float* __restrict__ b_e,
    const __bf16* __restrict__ GwT, const __bf16* __restrict__ WeT,
    __bf16* __restrict__ state, int* __restrict__ flags,
    float* __restrict__ out)
{
    __shared__ __align__(16) __bf16 wlds[4][16][1024];
    __shared__ __align__(16) __bf16 welds[16][512];

    const int tid = threadIdx.x;
    const int bid = blockIdx.x;
    const int rblk = bid & 7;
    const int cblk = bid >> 3;
    const int j0 = cblk << 4;
    const int wave = tid >> 6;
    const int lane = tid & 63;
    const int alr = lane & 15;   // weight row j (A-frag row)
    const int hq = lane >> 4;    // k-subgroup / C j-quad
    const int kbase = hq * 8;

    // ---- stage weights into LDS, swizzled (once) ----
    for (int e = tid * 8; e < 4 * 16 * 1024; e += 256 * 8) {
        const int g = e >> 14;
        const int j = (e >> 10) & 15;
        const int k = e & 1023;
        *(uint4*)&wlds[g][j][SWZ(j, k)] =
            *(const uint4*)&GwT[((size_t)(g * 512 + j0 + j) << 10) + k];
    }
    for (int e = tid * 8; e < 16 * 512; e += 256 * 8) {
        const int j = e >> 9;
        const int k = e & 511;
        *(uint4*)&welds[j][SWZ(j, k)] =
            *(const uint4*)&WeT[((size_t)(j0 + j) << 9) + k];
    }
    __syncthreads();

    // gates k<256 weight fragments in registers (128 VGPR)
    bf16x8 wxr[8][4];
    #pragma unroll
    for (int kk = 0; kk < 8; ++kk)
        #pragma unroll
        for (int g = 0; g < 4; ++g)
            wxr[kk][g] = *(const bf16x8*)&wlds[g][alr][SWZ(alr, kk * 32 + kbase)];

    const int brow = rblk * 64 + wave * 16 + alr;   // batch row
    const int jbase = j0 + hq * 4;                   // 4 consecutive j (C rows)
    const f32x4 Bi4 = *(const f32x4*)(b_i + jbase);
    const f32x4 Bf4 = *(const f32x4*)(b_f + jbase);
    const f32x4 Bc4 = *(const f32x4*)(b_c + jbase);
    const f32x4 Bo4 = *(const f32x4*)(b_o + jbase);
    const f32x4 Be4 = *(const f32x4*)(b_e + jbase);

    const float* xrow = x + (size_t)brow * S_SZ * D_SZ;
    const float* tsrow = tseq + (size_t)brow * S_SZ;
    const size_t hoff = (size_t)brow * H_SZ;         // elem offset of row
    float* outrow = out + (size_t)brow * S_SZ * H_SZ + jbase;

    // step-flag slots (128B stride) + per-lane poll pointer
    int* gflags = flags + rblk * 32 * 32;
    int* myflag = gflags + cblk * 32;
    const int* pollp = gflags + (lane & 31) * 32;

    // ---- XCD-locality check (one-time, proven rounds 6/9/10) ----
    int* xgrp = flags + 8192 + rblk * 32 * 32;
    unsigned xcc;
    asm volatile("s_getreg_b32 %0, hwreg(HW_REG_XCC_ID)" : "=s"(xcc));
    if (tid == 0)
        __hip_atomic_store(xgrp + cblk * 32, (int)xcc + 1,
                           __ATOMIC_RELAXED, __HIP_MEMORY_SCOPE_AGENT);
    int vx;
    const int* xpoll = xgrp + (lane & 31) * 32;
    for (;;) {
        vx = __hip_atomic_load(xpoll, __ATOMIC_RELAXED, __HIP_MEMORY_SCOPE_AGENT);
        if (__all(vx != 0)) break;
        __builtin_amdgcn_s_sleep(1);
    }
    const bool l2ok = __all(vx == __shfl(vx, 0, 64));

    // prologue: load + convert x[0]
    bf16x8 xbf[16];
    {
        f32x4 xf[32];
        #pragma unroll
        for (int kk = 0; kk < 16; ++kk) {
            xf[2 * kk]     = *(const f32x4*)(xrow + kk * 32 + kbase);
            xf[2 * kk + 1] = *(const f32x4*)(xrow + kk * 32 + kbase + 4);
        }
        #pragma unroll
        for (int kk = 0; kk < 16; ++kk) {
            f32x4 u = xf[2 * kk], v = xf[2 * kk + 1];
            bf16x8 a;
            a[0] = (__bf16)u[0]; a[1] = (__bf16)u[1]; a[2] = (__bf16)u[2]; a[3] = (__bf16)u[3];
            a[4] = (__bf16)v[0]; a[5] = (__bf16)v[1]; a[6] = (__bf16)v[2]; a[7] = (__bf16)v[3];
            xbf[kk] = a;
        }
    }

    for (int t = 0; t < S_SZ; ++t) {
        const __bf16* hp = state + (size_t)(t & 1) * STATE_PAR_ELEMS;
        const __bf16* cp = hp + (size_t)H_SZ * B_SZ;
        __bf16* hnx = state + (size_t)((t + 1) & 1) * STATE_PAR_ELEMS;
        __bf16* cnx = hnx + (size_t)H_SZ * B_SZ;

        // 1. issue all state loads up front (wave-uniform branch).
        //    l2ok: PLAIN 16B loads -- vL1 was invalidated after the barrier,
        //    so these miss L1 and are served fresh by the shared XCD L2.
        union HU { i32x4 q; u64 u[2]; bf16x8 v; };
        HU hs[16], cs[16];
        if (l2ok) {
            const __bf16* hb = hp + hoff + kbase;
            const __bf16* cb = cp + hoff + kbase;
            #pragma unroll
            for (int kk = 0; kk < 16; ++kk) {
                hs[kk].q = *(const i32x4*)(hb + kk * 32);
                cs[kk].q = *(const i32x4*)(cb + kk * 32);
            }
        } else {
            #pragma unroll
            for (int kk = 0; kk < 16; ++kk) {
                const u64* ph = (const u64*)(hp + hoff + kbase + kk * 32);
                const u64* pc = (const u64*)(cp + hoff + kbase + kk * 32);
                hs[kk].u[0] = coh_load(ph);
                hs[kk].u[1] = coh_load(ph + 1);
                cs[kk].u[0] = coh_load(pc);
                cs[kk].u[1] = coh_load(pc + 1);
            }
        }

        // accumulators pre-seeded with biases
        f32x4 a0 = Bi4, a1 = Bf4, a2 = Bc4, a3 = Bo4, a4 = Be4;

        // 2. x@U MFMAs while state loads fly (kk<8 weights from regs)
        #pragma unroll
        for (int kk = 0; kk < 16; ++kk) {
            bf16x8 w0, w1, w2, w3;
            if (kk < 8) {
                w0 = wxr[kk][0]; w1 = wxr[kk][1]; w2 = wxr[kk][2]; w3 = wxr[kk][3];
            } else {
                const int k = SWZ(alr, kk * 32 + kbase);
                w0 = *(const bf16x8*)&wlds[0][alr][k];
                w1 = *(const bf16x8*)&wlds[1][alr][k];
                w2 = *(const bf16x8*)&wlds[2][alr][k];
                w3 = *(const bf16x8*)&wlds[3][alr][k];
            }
            a0 = __builtin_amdgcn_mfma_f32_16x16x32_bf16(w0, xbf[kk], a0, 0, 0, 0);
            a1 = __builtin_amdgcn_mfma_f32_16x16x32_bf16(w1, xbf[kk], a1, 0, 0, 0);
            a2 = __builtin_amdgcn_mfma_f32_16x16x32_bf16(w2, xbf[kk], a2, 0, 0, 0);
            a3 = __builtin_amdgcn_mfma_f32_16x16x32_bf16(w3, xbf[kk], a3, 0, 0, 0);
        }

        // 3. h@V + cf@W_e (compiler inserts per-use vmcnt waits on hs/cs)
        #pragma unroll
        for (int kk = 0; kk < 16; ++kk) {
            const int k = SWZ(alr, 512 + kk * 32 + kbase);
            bf16x8 w0 = *(const bf16x8*)&wlds[0][alr][k];
            bf16x8 w1 = *(const bf16x8*)&wlds[1][alr][k];
            bf16x8 w2 = *(const bf16x8*)&wlds[2][alr][k];
            bf16x8 w3 = *(const bf16x8*)&wlds[3][alr][k];
            bf16x8 we = *(const bf16x8*)&welds[alr][SWZ(alr, kk * 32 + kbase)];
            a0 = __builtin_amdgcn_mfma_f32_16x16x32_bf16(w0, hs[kk].v, a0, 0, 0, 0);
            a1 = __builtin_amdgcn_mfma_f32_16x16x32_bf16(w1, hs[kk].v, a1, 0, 0, 0);
            a2 = __builtin_amdgcn_mfma_f32_16x16x32_bf16(w2, hs[kk].v, a2, 0, 0, 0);
            a3 = __builtin_amdgcn_mfma_f32_16x16x32_bf16(w3, hs[kk].v, a3, 0, 0, 0);
            a4 = __builtin_amdgcn_mfma_f32_16x16x32_bf16(we, cs[kk].v, a4, 0, 0, 0);
        }

        // 4. issue x[t+1] loads (latency hides under elementwise + stores)
        const int tp = (t + 1 < S_SZ) ? t + 1 : t;
        const float* xpn = xrow + (size_t)tp * D_SZ;
        f32x4 xf[32];
        #pragma unroll
        for (int kk = 0; kk < 16; ++kk) {
            xf[2 * kk]     = *(const f32x4*)(xpn + kk * 32 + kbase);
            xf[2 * kk + 1] = *(const f32x4*)(xpn + kk * 32 + kbase + 4);
        }

        // 5. elementwise: lane holds j = jbase..jbase+3 for batch row brow
        const float fa = (t + 1 < S_SZ) ? tsrow[t + 1] : 0.f;
        f32x4 hv4, cv4;
        union { bf16x4 v; u64 u; } ph8, pc8;
        #pragma unroll
        for (int e = 0; e < 4; ++e) {
            float it = sigmoidf_(a0[e]);
            float ft = sigmoidf_(a1[e]);
            float gt = tanhf_(a2[e]);
            float ot = sigmoidf_(a3[e]);
            float ctl = tanhf_(a4[e]);
            float cv = ft * ctl + it * gt;
            float hv = ot * tanhf_(cv);
            hv4[e] = hv; cv4[e] = cv;
            ph8.v[e] = (__bf16)hv;
            pc8.v[e] = (__bf16)(cv * fa);
        }
        __builtin_nontemporal_store(hv4, (f32x4*)(outrow + (size_t)t * H_SZ));
        if (t == S_SZ - 1) {
            float* tail = out + (size_t)B_SZ * S_SZ * H_SZ;
            *(f32x4*)(tail + hoff + jbase) = hv4;
            *(f32x4*)(tail + (size_t)B_SZ * H_SZ + hoff + jbase) = cv4;
        }

        // 6. convert x[t+1]
        #pragma unroll
        for (int kk = 0; kk < 16; ++kk) {
            f32x4 u = xf[2 * kk], v = xf[2 * kk + 1];
            bf16x8 a;
            a[0] = (__bf16)u[0]; a[1] = (__bf16)u[1]; a[2] = (__bf16)u[2]; a[3] = (__bf16)u[3];
            a[4] = (__bf16)v[0]; a[5] = (__bf16)v[1]; a[6] = (__bf16)v[2]; a[7] = (__bf16)v[3];
            xbf[kk] = a;
        }

        // 7. publish state. l2ok: plain write-through stores -> shared XCD L2
        //    (drained by syncthreads' vmcnt(0) before the flag release).
        if (l2ok) {
            *(u64*)(hnx + hoff + jbase) = ph8.u;
            *(u64*)(cnx + hoff + jbase) = pc8.u;
        } else {
            coh_store((u64*)(hnx + hoff + jbase), ph8.u);
            coh_store((u64*)(cnx + hoff + jbase), pc8.u);
        }

        // 8. flag barrier (round-5 protocol) + per-step vL1 invalidate on the
        //    fast path (acquire: the only incoherent cache inside an XCD).
        if (t < S_SZ - 1) {
            __syncthreads();   // s_waitcnt vmcnt(0): state stores in L2
            if (tid == 0)
                __hip_atomic_store(myflag, t + 1, __ATOMIC_RELAXED,
                                   __HIP_MEMORY_SCOPE_AGENT);
            const int target = t + 1;
            for (;;) {
                int v = __hip_atomic_load(pollp, __ATOMIC_RELAXED,
                                          __HIP_MEMORY_SCOPE_AGENT);
                if (__all(v >= target)) break;
                __builtin_amdgcn_s_sleep(2);
            }
            if (l2ok)
                asm volatile("buffer_inv sc0" ::: "memory");  // vL1 only
            __builtin_amdgcn_sched_barrier(0);
        }
    }
}

extern "C" void kernel_launch(void* const* d_in, const int* in_sizes, int n_in,
                              void* d_out, int out_size, void* d_ws, size_t ws_size,
                              hipStream_t stream) {
    const float* x  = (const float*)d_in[0];
    const float* ts = (const float*)d_in[1];
    const float* We = (const float*)d_in[2];
    const float* be = (const float*)d_in[3];
    const float* Ui = (const float*)d_in[4];
    const float* Vi = (const float*)d_in[5];
    const float* bi = (const float*)d_in[6];
    const float* Uf = (const float*)d_in[7];
    const float* Vf = (const float*)d_in[8];
    const float* bf = (const float*)d_in[9];
    const float* Uc = (const float*)d_in[10];
    const float* Vc = (const float*)d_in[11];
    const float* bc = (const float*)d_in[12];
    const float* Uo = (const float*)d_in[13];
    const float* Vo = (const float*)d_in[14];
    const float* bo = (const float*)d_in[15];

    char* ws = (char*)d_ws;
    int* flags = (int*)ws;
    __bf16* state = (__bf16*)(ws + STATE_OFF);
    __bf16* GwT = (__bf16*)(ws + GWT_OFF_BYTES);
    __bf16* WeT = (__bf16*)(ws + WET_OFF_BYTES);

    // zero flags (step + xcc) + parity-0 state (h0 = c0 = 0)
    hipMemsetAsync(ws, 0, FLAGS_BYTES + 1048576, stream);
    prep_weights<<<2560, 256, 0, stream>>>(We, Ui, Vi, Uf, Vf, Uc, Vc, Uo, Vo, GwT, WeT);
    lstm_persist<<<256, 256, 0, stream>>>(x, ts, bi, bf, bc, bo, be, GwT, WeT,
                                          state, flags, (float*)d_out);
}

// Round 13
// 1858.218 us; speedup vs baseline: 2.3177x; 1.1769x over previous
//
#include <hip/hip_runtime.h>

#define B_SZ 512
#define S_SZ 256
#define D_SZ 512
#define H_SZ 512

typedef __bf16 bf16x8 __attribute__((ext_vector_type(8)));
typedef __bf16 bf16x4 __attribute__((ext_vector_type(4)));
typedef float f32x4 __attribute__((ext_vector_type(4)));
typedef int i32x4 __attribute__((ext_vector_type(4)));
typedef unsigned long long u64;

// ---------------- ws layout (bytes) ----------------
// [0, 32KB)       : step flags: 8 groups x 32 WG-slots x 128B
// [32KB, 64KB)    : xcc flags:  8 groups x 32 WG-slots x 128B
// [64KB, +1MB)    : state parity 0: h0 (512x512 bf16) then cf0 (c*f_att)
// [+1MB, +2MB)    : state parity 1
// [2162688, +4MB) : GwT 4*512*1024 bf16 (g, j, k)
// [6356992, +.5MB): WeT 512*512 bf16 (j, k)
// [6881280, +128MB): x_bf16 (optional, if ws_size permits)
#define FLAGS_BYTES 65536
#define STATE_OFF FLAGS_BYTES
#define STATE_PAR_ELEMS (2 * H_SZ * B_SZ)
#define GWT_OFF_BYTES (STATE_OFF + 2097152)
#define WET_OFF_BYTES (GWT_OFF_BYTES + 4194304)
#define XB_OFF_BYTES (WET_OFF_BYTES + 524288)
#define XB_BYTES ((size_t)B_SZ * S_SZ * D_SZ * 2)

// XOR swizzle: 2-way max bank aliasing on ds_read_b128 (free per m136)
#define SWZ(j, k) ((k) ^ (((j) & 7) << 3) ^ ((((j) >> 3) & 1) << 6))

__device__ __forceinline__ float sigmoidf_(float v) {
    return 1.f / (1.f + __expf(-v));
}
__device__ __forceinline__ float tanhf_(float v) {
    return 1.f - 2.f / (1.f + __expf(2.f * v));
}

// LLC-coherent accesses (fallback + flag protocol): relaxed agent atomics ->
// sc0 sc1 on BOTH store and load sides (same coherence point => live).
// Proven rounds 2/4/5/11. [R12 lesson: never mix sc-scopes across a
// signal/poll pair -- volatile store (LLC) + sc0 poll (L2) deadlocks.]
__device__ __forceinline__ u64 coh_load(const u64* p) {
    return __hip_atomic_load(p, __ATOMIC_RELAXED, __HIP_MEMORY_SCOPE_AGENT);
}
__device__ __forceinline__ void coh_store(u64* p, u64 v) {
    __hip_atomic_store(p, v, __ATOMIC_RELAXED, __HIP_MEMORY_SCOPE_AGENT);
}

__global__ __launch_bounds__(256) void prep_weights(
    const float* __restrict__ We,
    const float* __restrict__ Ui, const float* __restrict__ Vi,
    const float* __restrict__ Uf, const float* __restrict__ Vf,
    const float* __restrict__ Uc, const float* __restrict__ Vc,
    const float* __restrict__ Uo, const float* __restrict__ Vo,
    __bf16* __restrict__ GwT, __bf16* __restrict__ WeT)
{
    const int bid = blockIdx.x;
    const int tid = threadIdx.x;
    if (bid < 2048) {
        const int g = bid >> 9;
        const int j = bid & 511;
        const float* U = (g == 0) ? Ui : (g == 1) ? Uf : (g == 2) ? Uc : Uo;
        const float* V = (g == 0) ? Vi : (g == 1) ? Vf : (g == 2) ? Vc : Vo;
        __bf16* dst = GwT + ((size_t)(g * 512 + j) << 10);
        for (int k = tid; k < 1024; k += 256) {
            float v = (k < 512) ? U[k * 512 + j] : V[(k - 512) * 512 + j];
            dst[k] = (__bf16)v;
        }
    } else {
        const int j = bid - 2048;
        __bf16* dst = WeT + ((size_t)j << 9);
        for (int k = tid; k < 512; k += 256) {
            dst[k] = (__bf16)We[k * 512 + j];
        }
    }
}

// One-time x f32 -> bf16 (same rounding the recurrent loop applied per step:
// numerics identical; halves per-step x load issue, kills 128 cvt/thread/step)
__global__ __launch_bounds__(256) void xcvt(const float* __restrict__ x,
                                            __bf16* __restrict__ xb)
{
    const size_t i = ((size_t)blockIdx.x * 256 + threadIdx.x) * 8;
    f32x4 a = *(const f32x4*)(x + i);
    f32x4 b = *(const f32x4*)(x + i + 4);
    bf16x8 o;
    o[0] = (__bf16)a[0]; o[1] = (__bf16)a[1]; o[2] = (__bf16)a[2]; o[3] = (__bf16)a[3];
    o[4] = (__bf16)b[0]; o[5] = (__bf16)b[1]; o[6] = (__bf16)b[2]; o[7] = (__bf16)b[3];
    *(bf16x8*)(xb + i) = o;
}

// Persistent recurrent kernel. 256 WGs x 256 thr, 1 WG/CU (144KB LDS).
// WG (rblk=bid&7, cblk=bid>>3): batch rows [rblk*64,+64) x cols [cblk*16,+16).
// Sync/coherence = ROUND-11 PROVEN RECIPE, unchanged: agent-atomic flag
// barrier; l2ok state exchange = plain write-through stores + plain 16B loads
// + per-step `buffer_inv sc0` (vL1 invalidate) after the poll.
template <bool XB>
__global__ __launch_bounds__(256, 1) void lstm_persist(
    const float* __restrict__ x, const __bf16* __restrict__ xb,
    const float* __restrict__ tseq,
    const float* __restrict__ b_i, const float* __restrict__ b_f,
    const float* __restrict__ b_c, const float* __restrict__ b_o,
    const float* __restrict__ b_e,
    const __bf16* __restrict__ GwT, const __bf16* __restrict__ WeT,
    __bf16* __restrict__ state, int* __restrict__ flags,
    float* __restrict__ out)
{
    __shared__ __align__(16) __bf16 wlds[4][16][1024];
    __shared__ __align__(16) __bf16 welds[16][512];

    const int tid = threadIdx.x;
    const int bid = blockIdx.x;
    const int rblk = bid & 7;
    const int cblk = bid >> 3;
    const int j0 = cblk << 4;
    const int wave = tid >> 6;
    const int lane = tid & 63;
    const int alr = lane & 15;   // weight row j (A-frag row)
    const int hq = lane >> 4;    // k-subgroup / C j-quad
    const int kbase = hq * 8;

    // ---- stage weights into LDS, swizzled (once) ----
    for (int e = tid * 8; e < 4 * 16 * 1024; e += 256 * 8) {
        const int g = e >> 14;
        const int j = (e >> 10) & 15;
        const int k = e & 1023;
        *(uint4*)&wlds[g][j][SWZ(j, k)] =
            *(const uint4*)&GwT[((size_t)(g * 512 + j0 + j) << 10) + k];
    }
    for (int e = tid * 8; e < 16 * 512; e += 256 * 8) {
        const int j = e >> 9;
        const int k = e & 511;
        *(uint4*)&welds[j][SWZ(j, k)] =
            *(const uint4*)&WeT[((size_t)(j0 + j) << 9) + k];
    }
    __syncthreads();

    // gates k<256 weight fragments in registers (128 VGPR)
    bf16x8 wxr[8][4];
    #pragma unroll
    for (int kk = 0; kk < 8; ++kk)
        #pragma unroll
        for (int g = 0; g < 4; ++g)
            wxr[kk][g] = *(const bf16x8*)&wlds[g][alr][SWZ(alr, kk * 32 + kbase)];

    const int brow = rblk * 64 + wave * 16 + alr;   // batch row
    const int jbase = j0 + hq * 4;                   // 4 consecutive j (C rows)
    const f32x4 Bi4 = *(const f32x4*)(b_i + jbase);
    const f32x4 Bf4 = *(const f32x4*)(b_f + jbase);
    const f32x4 Bc4 = *(const f32x4*)(b_c + jbase);
    const f32x4 Bo4 = *(const f32x4*)(b_o + jbase);
    const f32x4 Be4 = *(const f32x4*)(b_e + jbase);

    const float* xrow = x + (size_t)brow * S_SZ * D_SZ;
    const __bf16* xrowb = XB ? xb + (size_t)brow * S_SZ * D_SZ : nullptr;
    const float* tsrow = tseq + (size_t)brow * S_SZ;
    const size_t hoff = (size_t)brow * H_SZ;         // elem offset of row
    float* outrow = out + (size_t)brow * S_SZ * H_SZ + jbase;

    // step-flag slots (128B stride) + per-lane poll pointer
    int* gflags = flags + rblk * 32 * 32;
    int* myflag = gflags + cblk * 32;
    const int* pollp = gflags + (lane & 31) * 32;

    // ---- XCD-locality check (one-time, proven rounds 6/9/10/11) ----
    int* xgrp = flags + 8192 + rblk * 32 * 32;
    unsigned xcc;
    asm volatile("s_getreg_b32 %0, hwreg(HW_REG_XCC_ID)" : "=s"(xcc));
    if (tid == 0)
        __hip_atomic_store(xgrp + cblk * 32, (int)xcc + 1,
                           __ATOMIC_RELAXED, __HIP_MEMORY_SCOPE_AGENT);
    int vx;
    const int* xpoll = xgrp + (lane & 31) * 32;
    for (;;) {
        vx = __hip_atomic_load(xpoll, __ATOMIC_RELAXED, __HIP_MEMORY_SCOPE_AGENT);
        if (__all(vx != 0)) break;
        __builtin_amdgcn_s_sleep(1);
    }
    const bool l2ok = __all(vx == __shfl(vx, 0, 64));

    // prologue: x[0] fragments
    bf16x8 xbf[16];
    if constexpr (XB) {
        #pragma unroll
        for (int kk = 0; kk < 16; ++kk)
            xbf[kk] = *(const bf16x8*)(xrowb + kk * 32 + kbase);
    } else {
        f32x4 xf0[32];
        #pragma unroll
        for (int kk = 0; kk < 16; ++kk) {
            xf0[2 * kk]     = *(const f32x4*)(xrow + kk * 32 + kbase);
            xf0[2 * kk + 1] = *(const f32x4*)(xrow + kk * 32 + kbase + 4);
        }
        #pragma unroll
        for (int kk = 0; kk < 16; ++kk) {
            f32x4 u = xf0[2 * kk], v = xf0[2 * kk + 1];
            bf16x8 a;
            a[0] = (__bf16)u[0]; a[1] = (__bf16)u[1]; a[2] = (__bf16)u[2]; a[3] = (__bf16)u[3];
            a[4] = (__bf16)v[0]; a[5] = (__bf16)v[1]; a[6] = (__bf16)v[2]; a[7] = (__bf16)v[3];
            xbf[kk] = a;
        }
    }

    for (int t = 0; t < S_SZ; ++t) {
        const __bf16* hp = state + (size_t)(t & 1) * STATE_PAR_ELEMS;
        const __bf16* cp = hp + (size_t)H_SZ * B_SZ;
        __bf16* hnx = state + (size_t)((t + 1) & 1) * STATE_PAR_ELEMS;
        __bf16* cnx = hnx + (size_t)H_SZ * B_SZ;

        // 1. early-issue: attenuation scalar + all state loads.
        //    l2ok: PLAIN 16B loads (vL1 invalidated after last barrier ->
        //    served fresh from the shared XCD L2).
        const float fa = (t + 1 < S_SZ) ? tsrow[t + 1] : 0.f;
        union HU { i32x4 q; u64 u[2]; bf16x8 v; };
        HU hs[16], cs[16];
        if (l2ok) {
            const __bf16* hb = hp + hoff + kbase;
            const __bf16* cb = cp + hoff + kbase;
            #pragma unroll
            for (int kk = 0; kk < 16; ++kk) {
                hs[kk].q = *(const i32x4*)(hb + kk * 32);
                cs[kk].q = *(const i32x4*)(cb + kk * 32);
            }
        } else {
            #pragma unroll
            for (int kk = 0; kk < 16; ++kk) {
                const u64* ph = (const u64*)(hp + hoff + kbase + kk * 32);
                const u64* pc = (const u64*)(cp + hoff + kbase + kk * 32);
                hs[kk].u[0] = coh_load(ph);
                hs[kk].u[1] = coh_load(ph + 1);
                cs[kk].u[0] = coh_load(pc);
                cs[kk].u[1] = coh_load(pc + 1);
            }
        }

        // accumulators pre-seeded with biases
        f32x4 a0 = Bi4, a1 = Bf4, a2 = Bc4, a3 = Bo4, a4 = Be4;

        // 2. x@U MFMAs while state loads fly (kk<8 weights from regs)
        #pragma unroll
        for (int kk = 0; kk < 16; ++kk) {
            bf16x8 w0, w1, w2, w3;
            if (kk < 8) {
                w0 = wxr[kk][0]; w1 = wxr[kk][1]; w2 = wxr[kk][2]; w3 = wxr[kk][3];
            } else {
                const int k = SWZ(alr, kk * 32 + kbase);
                w0 = *(const bf16x8*)&wlds[0][alr][k];
                w1 = *(const bf16x8*)&wlds[1][alr][k];
                w2 = *(const bf16x8*)&wlds[2][alr][k];
                w3 = *(const bf16x8*)&wlds[3][alr][k];
            }
            a0 = __builtin_amdgcn_mfma_f32_16x16x32_bf16(w0, xbf[kk], a0, 0, 0, 0);
            a1 = __builtin_amdgcn_mfma_f32_16x16x32_bf16(w1, xbf[kk], a1, 0, 0, 0);
            a2 = __builtin_amdgcn_mfma_f32_16x16x32_bf16(w2, xbf[kk], a2, 0, 0, 0);
            a3 = __builtin_amdgcn_mfma_f32_16x16x32_bf16(w3, xbf[kk], a3, 0, 0, 0);
        }

        // 3. h@V + cf@W_e (compiler inserts per-use vmcnt waits on hs/cs)
        #pragma unroll
        for (int kk = 0; kk < 16; ++kk) {
            const int k = SWZ(alr, 512 + kk * 32 + kbase);
            bf16x8 w0 = *(const bf16x8*)&wlds[0][alr][k];
            bf16x8 w1 = *(const bf16x8*)&wlds[1][alr][k];
            bf16x8 w2 = *(const bf16x8*)&wlds[2][alr][k];
            bf16x8 w3 = *(const bf16x8*)&wlds[3][alr][k];
            bf16x8 we = *(const bf16x8*)&welds[alr][SWZ(alr, kk * 32 + kbase)];
            a0 = __builtin_amdgcn_mfma_f32_16x16x32_bf16(w0, hs[kk].v, a0, 0, 0, 0);
            a1 = __builtin_amdgcn_mfma_f32_16x16x32_bf16(w1, hs[kk].v, a1, 0, 0, 0);
            a2 = __builtin_amdgcn_mfma_f32_16x16x32_bf16(w2, hs[kk].v, a2, 0, 0, 0);
            a3 = __builtin_amdgcn_mfma_f32_16x16x32_bf16(w3, hs[kk].v, a3, 0, 0, 0);
            a4 = __builtin_amdgcn_mfma_f32_16x16x32_bf16(we, cs[kk].v, a4, 0, 0, 0);
        }

        // 4. x[t+1] prefetch (xbf dead after phase 2; latency hides under
        //    phases 5-8, drained by the barrier's vmcnt(0))
        const int tp = (t + 1 < S_SZ) ? t + 1 : t;
        f32x4 xf[32];
        if constexpr (XB) {
            const __bf16* xpn = xrowb + (size_t)tp * D_SZ;
            #pragma unroll
            for (int kk = 0; kk < 16; ++kk)
                xbf[kk] = *(const bf16x8*)(xpn + kk * 32 + kbase);
        } else {
            const float* xpn = xrow + (size_t)tp * D_SZ;
            #pragma unroll
            for (int kk = 0; kk < 16; ++kk) {
                xf[2 * kk]     = *(const f32x4*)(xpn + kk * 32 + kbase);
                xf[2 * kk + 1] = *(const f32x4*)(xpn + kk * 32 + kbase + 4);
            }
        }

        // 5. elementwise: lane holds j = jbase..jbase+3 for batch row brow
        f32x4 hv4, cv4;
        union { bf16x4 v; u64 u; } ph8, pc8;
        #pragma unroll
        for (int e = 0; e < 4; ++e) {
            float it = sigmoidf_(a0[e]);
            float ft = sigmoidf_(a1[e]);
            float gt = tanhf_(a2[e]);
            float ot = sigmoidf_(a3[e]);
            float ctl = tanhf_(a4[e]);
            float cv = ft * ctl + it * gt;
            float hv = ot * tanhf_(cv);
            hv4[e] = hv; cv4[e] = cv;
            ph8.v[e] = (__bf16)hv;
            pc8.v[e] = (__bf16)(cv * fa);
        }
        __builtin_nontemporal_store(hv4, (f32x4*)(outrow + (size_t)t * H_SZ));
        if (t == S_SZ - 1) {
            float* tail = out + (size_t)B_SZ * S_SZ * H_SZ;
            *(f32x4*)(tail + hoff + jbase) = hv4;
            *(f32x4*)(tail + (size_t)B_SZ * H_SZ + hoff + jbase) = cv4;
        }

        // 6. convert x[t+1] (f32 fallback path only)
        if constexpr (!XB) {
            #pragma unroll
            for (int kk = 0; kk < 16; ++kk) {
                f32x4 u = xf[2 * kk], v = xf[2 * kk + 1];
                bf16x8 a;
                a[0] = (__bf16)u[0]; a[1] = (__bf16)u[1]; a[2] = (__bf16)u[2]; a[3] = (__bf16)u[3];
                a[4] = (__bf16)v[0]; a[5] = (__bf16)v[1]; a[6] = (__bf16)v[2]; a[7] = (__bf16)v[3];
                xbf[kk] = a;
            }
        }

        // 7. publish state (l2ok: plain write-through -> shared XCD L2)
        if (l2ok) {
            *(u64*)(hnx + hoff + jbase) = ph8.u;
            *(u64*)(cnx + hoff + jbase) = pc8.u;
        } else {
            coh_store((u64*)(hnx + hoff + jbase), ph8.u);
            coh_store((u64*)(cnx + hoff + jbase), pc8.u);
        }

        // 8. flag barrier: ROUND-11 PROTOCOL VERBATIM (agent atomics both
        //    sides = same coherence point = live), then vL1 invalidate on the
        //    fast path (acquire for the plain state loads).
        if (t < S_SZ - 1) {
            __syncthreads();   // s_waitcnt vmcnt(0): state stores in L2
            if (tid == 0)
                __hip_atomic_store(myflag, t + 1, __ATOMIC_RELAXED,
                                   __HIP_MEMORY_SCOPE_AGENT);
            const int target = t + 1;
            for (;;) {
                int v = __hip_atomic_load(pollp, __ATOMIC_RELAXED,
                                          __HIP_MEMORY_SCOPE_AGENT);
                if (__all(v >= target)) break;
                __builtin_amdgcn_s_sleep(2);
            }
            if (l2ok)
                asm volatile("buffer_inv sc0" ::: "memory");  // vL1 only
            __builtin_amdgcn_sched_barrier(0);
        }
    }
}

extern "C" void kernel_launch(void* const* d_in, const int* in_sizes, int n_in,
                              void* d_out, int out_size, void* d_ws, size_t ws_size,
                              hipStream_t stream) {
    const float* x  = (const float*)d_in[0];
    const float* ts = (const float*)d_in[1];
    const float* We = (const float*)d_in[2];
    const float* be = (const float*)d_in[3];
    const float* Ui = (const float*)d_in[4];
    const float* Vi = (const float*)d_in[5];
    const float* bi = (const float*)d_in[6];
    const float* Uf = (const float*)d_in[7];
    const float* Vf = (const float*)d_in[8];
    const float* bf = (const float*)d_in[9];
    const float* Uc = (const float*)d_in[10];
    const float* Vc = (const float*)d_in[11];
    const float* bc = (const float*)d_in[12];
    const float* Uo = (const float*)d_in[13];
    const float* Vo = (const float*)d_in[14];
    const float* bo = (const float*)d_in[15];

    char* ws = (char*)d_ws;
    int* flags = (int*)ws;
    __bf16* state = (__bf16*)(ws + STATE_OFF);
    __bf16* GwT = (__bf16*)(ws + GWT_OFF_BYTES);
    __bf16* WeT = (__bf16*)(ws + WET_OFF_BYTES);

    // zero flags (step + xcc) + parity-0 state (h0 = c0 = 0)
    hipMemsetAsync(ws, 0, FLAGS_BYTES + 1048576, stream);
    prep_weights<<<2560, 256, 0, stream>>>(We, Ui, Vi, Uf, Vf, Uc, Vc, Uo, Vo, GwT, WeT);

    if (ws_size >= (size_t)XB_OFF_BYTES + XB_BYTES) {
        __bf16* xb = (__bf16*)(ws + XB_OFF_BYTES);
        xcvt<<<(int)(B_SZ * S_SZ * D_SZ / 8 / 256), 256, 0, stream>>>(x, xb);
        lstm_persist<true><<<256, 256, 0, stream>>>(x, xb, ts, bi, bf, bc, bo, be,
                                                    GwT, WeT, state, flags,
                                                    (float*)d_out);
    } else {
        lstm_persist<false><<<256, 256, 0, stream>>>(x, nullptr, ts, bi, bf, bc, bo,
                                                     be, GwT, WeT, state, flags,
                                                     (float*)d_out);
    }
}